// Round 1
// baseline (6422.337 us; speedup 1.0000x reference)
//
#include <hip/hip_runtime.h>
#include <math.h>

typedef long long ll;

#define BM 64
#define BN 64
#define BK 16

// Generic strided batched GEMM:
//   C[z][m,n] (+)= sum_k A[z][m,k] * B[z][k,n]
// A element at Abase + z*a_bs + m*a_rs + k*a_cs   (requires a_cs==1 or a_rs==1)
// B element at Bbase + z*b_bs + k*b_rs + n*b_cs   (requires b_cs==1 or b_rs==1)
// C element at Cbase + z*c_bs + m*c_rs + n        (contiguous along n)
// Assumes M%64==0, N%64==0, K%16==0, all strides multiples of 4 (float4 loads).
// tri_skip: skip tiles entirely above the diagonal (S = causal scores).
// k_clamp : clamp K-loop to m0+BM (PV GEMM: P[t,s]==0 for s>t).
__global__ __launch_bounds__(256)
void gemm_f32(const float* __restrict__ Abase, const float* __restrict__ Bbase,
              float* __restrict__ Cbase,
              int M, int N, int K,
              int a_rs, int a_cs, ll a_bs,
              int b_rs, int b_cs, ll b_bs,
              int c_rs, ll c_bs,
              int tri_skip, int k_clamp, int accum)
{
    const int m0 = blockIdx.y * BM;
    const int n0 = blockIdx.x * BN;
    if (tri_skip && n0 >= m0 + BM) return;

    const float* A = Abase + (ll)blockIdx.z * a_bs;
    const float* B = Bbase + (ll)blockIdx.z * b_bs;
    float*       C = Cbase + (ll)blockIdx.z * c_bs;

    int Keff = K;
    if (k_clamp) { int kl = m0 + BM; if (kl < Keff) Keff = kl; }

    __shared__ __align__(16) float As[BK][BM + 4];
    __shared__ __align__(16) float Bs[BK][BN + 4];

    const int tid = threadIdx.x;
    const int ty = tid >> 4;   // 0..15
    const int tx = tid & 15;   // 0..15

    float acc[4][4];
#pragma unroll
    for (int i = 0; i < 4; ++i)
#pragma unroll
        for (int j = 0; j < 4; ++j) acc[i][j] = 0.0f;

    for (int k0 = 0; k0 < Keff; k0 += BK) {
        // ---- stage A tile: As[kk][mm] = A[m0+mm, k0+kk]
        if (a_cs == 1) {
            const int mm = tid >> 2;
            const int kq = (tid & 3) * 4;
            float4 v = *(const float4*)(A + (ll)(m0 + mm) * a_rs + (k0 + kq));
            As[kq + 0][mm] = v.x;
            As[kq + 1][mm] = v.y;
            As[kq + 2][mm] = v.z;
            As[kq + 3][mm] = v.w;
        } else { // a_rs == 1: contiguous along m
            const int kk  = tid >> 4;
            const int mm0 = (tid & 15) * 4;
            float4 v = *(const float4*)(A + (ll)(k0 + kk) * a_cs + (m0 + mm0));
            *(float4*)&As[kk][mm0] = v;
        }
        // ---- stage B tile: Bs[kk][nn] = B[k0+kk, n0+nn]
        if (b_cs == 1) {
            const int kk  = tid >> 4;
            const int nn0 = (tid & 15) * 4;
            float4 v = *(const float4*)(B + (ll)(k0 + kk) * b_rs + (n0 + nn0));
            *(float4*)&Bs[kk][nn0] = v;
        } else { // b_rs == 1: contiguous along k
            const int nn = tid >> 2;
            const int kq = (tid & 3) * 4;
            float4 v = *(const float4*)(B + (ll)(n0 + nn) * b_cs + (k0 + kq));
            Bs[kq + 0][nn] = v.x;
            Bs[kq + 1][nn] = v.y;
            Bs[kq + 2][nn] = v.z;
            Bs[kq + 3][nn] = v.w;
        }
        __syncthreads();
#pragma unroll
        for (int kk = 0; kk < BK; ++kk) {
            float4 a = *(const float4*)&As[kk][ty * 4];
            float4 b = *(const float4*)&Bs[kk][tx * 4];
            float av[4] = {a.x, a.y, a.z, a.w};
            float bv[4] = {b.x, b.y, b.z, b.w};
#pragma unroll
            for (int i = 0; i < 4; ++i)
#pragma unroll
                for (int j = 0; j < 4; ++j) acc[i][j] += av[i] * bv[j];
        }
        __syncthreads();
    }

#pragma unroll
    for (int i = 0; i < 4; ++i) {
        ll off = (ll)(m0 + ty * 4 + i) * c_rs + (n0 + tx * 4);
        float4 r = make_float4(acc[i][0], acc[i][1], acc[i][2], acc[i][3]);
        if (accum) {
            float4 o = *(const float4*)&C[off];
            r.x += o.x; r.y += o.y; r.z += o.z; r.w += o.w;
        }
        *(float4*)&C[off] = r;
    }
}

// In-place rope on buf laid out [outer = (b*T+t)*H + h][64], pairs (2j, 2j+1).
// cos/sin are [T][32].
__global__ void rope_kernel(float* __restrict__ buf,
                            const float* __restrict__ c,
                            const float* __restrict__ s,
                            int total_pairs, int H, int T)
{
    int idx = blockIdx.x * 256 + threadIdx.x;
    if (idx >= total_pairs) return;
    int j = idx & 31;
    int o = idx >> 5;            // (b*T + t)*H + h
    int t = (o / H) % T;
    float cv = c[t * 32 + j];
    float sv = s[t * 32 + j];
    float re = buf[(ll)o * 64 + 2 * j];
    float im = buf[(ll)o * 64 + 2 * j + 1];
    buf[(ll)o * 64 + 2 * j]     = re * cv - im * sv;
    buf[(ll)o * 64 + 2 * j + 1] = re * sv + im * cv;
}

// Causal softmax in place on S[z][t][0..T): scales logits, softmax over s<=t,
// zeroes s>t (so the PV GEMM can read the full row).
__global__ __launch_bounds__(256)
void softmax_causal(float* __restrict__ Sbase, int T, float scale)
{
    const int t = blockIdx.x;
    float* row = Sbase + (ll)blockIdx.y * T * T + (ll)t * T;
    const int tid = threadIdx.x;
    const int n = t + 1;

    __shared__ float red[256];

    float m = -1e30f;
    for (int s = tid; s < n; s += 256) m = fmaxf(m, row[s] * scale);
    red[tid] = m;
    __syncthreads();
    for (int off = 128; off > 0; off >>= 1) {
        if (tid < off) red[tid] = fmaxf(red[tid], red[tid + off]);
        __syncthreads();
    }
    m = red[0];
    __syncthreads();

    float lsum = 0.0f;
    for (int s = tid; s < n; s += 256) {
        float e = __expf(row[s] * scale - m);
        row[s] = e;
        lsum += e;
    }
    red[tid] = lsum;
    __syncthreads();
    for (int off = 128; off > 0; off >>= 1) {
        if (tid < off) red[tid] += red[tid + off];
        __syncthreads();
    }
    float inv = 1.0f / red[0];
    __syncthreads();

    for (int s = tid; s < n; s += 256) row[s] *= inv;
    for (int s = n + tid; s < T; s += 256) row[s] = 0.0f;
}

static inline void gemm(hipStream_t st, const float* A, const float* B, float* Cp,
                        int M, int N, int K,
                        int a_rs, int a_cs, ll a_bs,
                        int b_rs, int b_cs, ll b_bs,
                        int c_rs, ll c_bs, int nb,
                        int tri = 0, int kcl = 0, int acc = 0)
{
    dim3 g(N / BN, M / BM, nb), bl(256);
    hipLaunchKernelGGL(gemm_f32, g, bl, 0, st, A, B, Cp, M, N, K,
                       a_rs, a_cs, a_bs, b_rs, b_cs, b_bs, c_rs, c_bs, tri, kcl, acc);
}

extern "C" void kernel_launch(void* const* d_in, const int* in_sizes, int n_in,
                              void* d_out, int out_size, void* d_ws, size_t ws_size,
                              hipStream_t stream)
{
    const float* x     = (const float*)d_in[0];
    const float* cosb  = (const float*)d_in[1];
    const float* sinb  = (const float*)d_in[2];
    const float* W_dq  = (const float*)d_in[3];
    const float* W_uq  = (const float*)d_in[4];
    const float* W_dkv = (const float*)d_in[5];
    const float* W_uk  = (const float*)d_in[6];
    const float* W_uv  = (const float*)d_in[7];
    const float* W_qr  = (const float*)d_in[8];
    const float* W_kr  = (const float*)d_in[9];
    const float* W_o   = (const float*)d_in[10];
    float* out = (float*)d_out;
    float* ws  = (float*)d_ws;

    const int Bb = 2, T = 2048, Cc = 2048, NH = 16, NLQ = 512, NLKV = 512, DHR = 64;
    const float scale = 0.07216878364870323f; // 1/sqrt(128+64)

    // ---- workspace layout (floats) ----
    float* k_eff = ws;                               // 16*512*512   = 4194304
    float* v_eff = k_eff + (ll)16 * 512 * 512;       // 16*512*128   = 1048576
    float* c_q   = v_eff + (ll)16 * 512 * 128;       // 2*2048*512   = 2097152
    float* c_kv  = c_q   + (ll)Bb * T * NLQ;         // 2*2048*512   = 2097152
    float* k_r   = c_kv  + (ll)Bb * T * NLKV;        // 2*2048*64    = 262144
    float* q_r   = k_r   + (ll)Bb * T * DHR;         // 2*2048*16*64 = 4194304
    float* k_abs = q_r   + (ll)Bb * T * NH * DHR;    // 2*512*2048   = 2097152 (chunk)
    float* Sbuf  = k_abs + (ll)2 * NLQ * T;          // 2*2048*2048  = 8388608 (chunk)
    float* ctx   = Sbuf  + (ll)2 * T * T;            // 2*2048*512   = 2097152 (chunk)
    // total = 26,476,544 floats = ~106 MB

    // ---- weight-only precomputes ----
    // k_eff[h,q,k] = sum_d W_uq[q*2048 + h*128 + d] * W_uk[h*65536 + d*512 + k]
    gemm(stream, W_uq, W_uk, k_eff, 512, 512, 128,
         2048, 1, 128,      512, 1, 65536,     512, 262144, NH);
    // v_eff[h,k,d] = sum_c W_uv[c*512 + k] * W_o[(h*128+d)*2048 + c]
    gemm(stream, W_uv, W_o, v_eff, 512, 128, 2048,
         1, 512, 0,         1, 2048, 262144,   128, 65536, NH);

    // ---- input projections ----
    // c_q[b,t,l] = sum_c x[b,t,c] * W_dq[l*2048+c]
    gemm(stream, x, W_dq, c_q, 2048, 512, 2048,
         2048, 1, (ll)T * Cc,   1, 2048, 0,    512, (ll)T * NLQ, Bb);
    // c_kv[b,t,k] = sum_c x * W_dkv
    gemm(stream, x, W_dkv, c_kv, 2048, 512, 2048,
         2048, 1, (ll)T * Cc,   1, 2048, 0,    512, (ll)T * NLKV, Bb);
    // c_kr -> k_r buffer (rope applied in place after)
    gemm(stream, x, W_kr, k_r, 2048, 64, 2048,
         2048, 1, (ll)T * Cc,   1, 2048, 0,    64, (ll)T * DHR, Bb);
    {
        int tp = Bb * T * 32;
        hipLaunchKernelGGL(rope_kernel, dim3((tp + 255) / 256), dim3(256), 0, stream,
                           k_r, cosb, sinb, tp, 1, T);
    }
    // c_qr -> q_r buffer: q_r[b,t, h*64+r] = sum_l c_q[b,t,l] * W_qr[(h*64+r)*512 + l]
    gemm(stream, c_q, W_qr, q_r, 2048, 1024, 512,
         512, 1, (ll)T * NLQ,   1, 512, 0,    1024, (ll)T * NH * DHR, Bb);
    {
        int tp = Bb * T * NH * 32;
        hipLaunchKernelGGL(rope_kernel, dim3((tp + 255) / 256), dim3(256), 0, stream,
                           q_r, cosb, sinb, tp, NH, T);
    }

    // ---- attention, 2 (b,h)-pairs per chunk ----
    for (int ci = 0; ci < 16; ++ci) {
        const int p0 = 2 * ci;
        const int b  = p0 >> 4;      // 16 pairs per batch; chunks never straddle b
        const int h0 = p0 & 15;

        // k_abs[z][l,s] = sum_k k_eff[h0+z, l, k] * c_kv[b, s, k]
        gemm(stream, k_eff + (ll)h0 * 262144, c_kv + (ll)b * T * NLKV, k_abs,
             512, 2048, 512,
             512, 1, 262144,    1, 512, 0,     2048, (ll)512 * 2048, 2);

        // S[z][t,s] = sum_l c_q[b,t,l] * k_abs[z][l,s]          (causal tiles only)
        gemm(stream, c_q + (ll)b * T * NLQ, k_abs, Sbuf,
             2048, 2048, 512,
             512, 1, 0,         2048, 1, (ll)512 * 2048,   2048, (ll)T * T, 2,
             /*tri*/1);

        // S[z][t,s] += sum_r q_r[b,t,h0+z,r] * k_r[b,s,r]
        gemm(stream, q_r + (ll)b * T * NH * DHR + (ll)h0 * 64, k_r + (ll)b * T * DHR, Sbuf,
             2048, 2048, 64,
             1024, 1, 64,       1, 64, 0,      2048, (ll)T * T, 2,
             /*tri*/1, 0, /*accum*/1);

        // scale + causal softmax in place (also zeroes the masked region)
        hipLaunchKernelGGL(softmax_causal, dim3(T, 2), dim3(256), 0, stream,
                           Sbuf, T, scale);

        // ctx[z][t,k] = sum_s P[z][t,s] * c_kv[b,s,k]           (K clamped causally)
        gemm(stream, Sbuf, c_kv + (ll)b * T * NLKV, ctx,
             2048, 512, 2048,
             2048, 1, (ll)T * T,   512, 1, 0,  512, (ll)T * NLKV, 2,
             0, /*kcl*/1);

        // y[b,t,(h0+z)*128+d] = sum_k ctx[z][t,k] * v_eff[h0+z,k,d]
        gemm(stream, ctx, v_eff + (ll)h0 * 65536, out + (ll)b * T * Cc + (ll)h0 * 128,
             2048, 128, 512,
             512, 1, (ll)T * NLKV,  128, 1, 65536,   2048, 128, 2);
    }

    (void)in_sizes; (void)n_in; (void)out_size; (void)ws_size;
}

// Round 2
// 2028.021 us; speedup vs baseline: 3.1668x; 3.1668x over previous
//
#include <hip/hip_runtime.h>
#include <hip/hip_bf16.h>
#include <math.h>

typedef long long ll;
typedef unsigned short ushort_t;
typedef __attribute__((ext_vector_type(8))) __bf16 bf16x8;
typedef __attribute__((ext_vector_type(4))) float f32x4;

// ---------------- helpers ----------------
__device__ __forceinline__ ushort_t f2bf(float f) {
    __hip_bfloat16 h = __float2bfloat16(f);   // RNE
    return *reinterpret_cast<ushort_t*>(&h);
}
__device__ __forceinline__ float bf2f(ushort_t u) {
    return __uint_as_float(((unsigned)u) << 16);
}

__device__ __forceinline__ void gld16(const void* g, void* l) {
    __builtin_amdgcn_global_load_lds(
        (const __attribute__((address_space(1))) unsigned int*)g,
        (__attribute__((address_space(3))) unsigned int*)l, 16, 0, 0);
}

// ---------------- bf16 MFMA GEMM (B^T form) ----------------
//   C[z][m,n] = sum_k A[z][m,k] * B[z][n,k]
// A,B bf16 K-contiguous; C fp32 or bf16, n contiguous.
// M%128==0, N%128==0, K%32==0; bases/strides 16B-aligned.
#define TM 128
#define TN 128
#define TKK 32

__global__ __launch_bounds__(256)
void gemm_bf16(const ushort_t* __restrict__ Ab, const ushort_t* __restrict__ Bb,
               void* __restrict__ Cb,
               int M, int N, int K,
               int a_rs, ll a_bs, int b_rs, ll b_bs,
               int c_rs, ll c_bs,
               int tri_skip, int k_clamp, int out_f32)
{
    const int m0 = blockIdx.y * TM;
    const int n0 = blockIdx.x * TN;
    if (tri_skip && n0 >= m0 + TM) return;   // fully above causal diagonal

    const ushort_t* A = Ab + (ll)blockIdx.z * a_bs;
    const ushort_t* B = Bb + (ll)blockIdx.z * b_bs;

    int Keff = K;
    if (k_clamp) { int kl = m0 + TM; if (kl < Keff) Keff = kl; }

    __shared__ ushort_t As[TM][TKK];   // [m][k], row = 64B
    __shared__ ushort_t Bs[TN][TKK];   // [n][k]

    const int tid  = threadIdx.x;
    const int w    = tid >> 6;
    const int l    = tid & 63;
    const int lo16 = l & 15;
    const int quad = l >> 4;
    const int wm0  = (w & 1) * 64;
    const int wn0  = (w >> 1) * 64;

    const int srow = l >> 2;        // staging row within 16-row segment
    const int scol = (l & 3) * 8;   // staging k-offset (16B)

    f32x4 acc[4][4];
    const f32x4 zero = {0.f, 0.f, 0.f, 0.f};
#pragma unroll
    for (int mi = 0; mi < 4; ++mi)
#pragma unroll
        for (int nj = 0; nj < 4; ++nj) acc[mi][nj] = zero;

    for (int k0 = 0; k0 < Keff; k0 += TKK) {
#pragma unroll
        for (int i = 0; i < 2; ++i) {
            const int seg = w * 2 + i;
            gld16(A + (ll)(m0 + seg * 16 + srow) * a_rs + (k0 + scol), &As[seg * 16][0]);
        }
#pragma unroll
        for (int i = 0; i < 2; ++i) {
            const int seg = w * 2 + i;
            gld16(B + (ll)(n0 + seg * 16 + srow) * b_rs + (k0 + scol), &Bs[seg * 16][0]);
        }
        __syncthreads();

        bf16x8 af[4], bfr[4];
#pragma unroll
        for (int mi = 0; mi < 4; ++mi)
            af[mi] = *(const bf16x8*)&As[wm0 + mi * 16 + lo16][quad * 8];
#pragma unroll
        for (int nj = 0; nj < 4; ++nj)
            bfr[nj] = *(const bf16x8*)&Bs[wn0 + nj * 16 + lo16][quad * 8];
#pragma unroll
        for (int mi = 0; mi < 4; ++mi)
#pragma unroll
            for (int nj = 0; nj < 4; ++nj)
                acc[mi][nj] = __builtin_amdgcn_mfma_f32_16x16x32_bf16(
                    af[mi], bfr[nj], acc[mi][nj], 0, 0, 0);
        __syncthreads();
    }

    if (out_f32) {
        float* C = (float*)Cb + (ll)blockIdx.z * c_bs;
#pragma unroll
        for (int mi = 0; mi < 4; ++mi)
#pragma unroll
            for (int r = 0; r < 4; ++r) {
                const ll row = m0 + wm0 + mi * 16 + quad * 4 + r;
                float* cr = C + row * (ll)c_rs + (n0 + wn0 + lo16);
#pragma unroll
                for (int nj = 0; nj < 4; ++nj) cr[nj * 16] = acc[mi][nj][r];
            }
    } else {
        ushort_t* C = (ushort_t*)Cb + (ll)blockIdx.z * c_bs;
#pragma unroll
        for (int mi = 0; mi < 4; ++mi)
#pragma unroll
            for (int r = 0; r < 4; ++r) {
                const ll row = m0 + wm0 + mi * 16 + quad * 4 + r;
                ushort_t* cr = C + row * (ll)c_rs + (n0 + wn0 + lo16);
#pragma unroll
                for (int nj = 0; nj < 4; ++nj) cr[nj * 16] = f2bf(acc[mi][nj][r]);
            }
    }
}

// ---------------- conversion / layout kernels ----------------
__global__ void cvt_f32_bf16(const float* __restrict__ in, ushort_t* __restrict__ out, ll n4)
{
    ll i = (ll)blockIdx.x * 256 + threadIdx.x;
    if (i >= n4) return;
    float4 v = *(const float4*)(in + i * 4);
    ushort4 u;
    u.x = f2bf(v.x); u.y = f2bf(v.y); u.z = f2bf(v.z); u.w = f2bf(v.w);
    *(ushort4*)(out + i * 4) = u;
}

__global__ void build_wkvr(const float* __restrict__ Wdkv, const float* __restrict__ Wkr,
                           ushort_t* __restrict__ out)
{
    ll i4 = ((ll)blockIdx.x * 256 + threadIdx.x) * 4;
    if (i4 >= (ll)640 * 2048) return;
    int row = (int)(i4 >> 11);
    int col = (int)(i4 & 2047);
    float4 v;
    if (row < 512)      v = *(const float4*)(Wdkv + (ll)row * 2048 + col);
    else if (row < 576) v = *(const float4*)(Wkr + (ll)(row - 512) * 2048 + col);
    else                v = make_float4(0.f, 0.f, 0.f, 0.f);
    ushort4 u;
    u.x = f2bf(v.x); u.y = f2bf(v.y); u.z = f2bf(v.z); u.w = f2bf(v.w);
    *(ushort4*)(out + i4) = u;
}

__global__ void transpose_f32_bf16(const float* __restrict__ in, ushort_t* __restrict__ out,
                                   int R, int C, ll in_bs, ll out_bs)
{
    __shared__ float tile[32][33];
    const float* I = in + (ll)blockIdx.z * in_bs;
    ushort_t*    O = out + (ll)blockIdx.z * out_bs;
    int r0 = blockIdx.y * 32, c0 = blockIdx.x * 32;
    int tx = threadIdx.x & 31, ty = threadIdx.x >> 5;
#pragma unroll
    for (int i = 0; i < 4; ++i)
        tile[ty + i * 8][tx] = I[(ll)(r0 + ty + i * 8) * C + (c0 + tx)];
    __syncthreads();
#pragma unroll
    for (int i = 0; i < 4; ++i)
        O[(ll)(c0 + ty + i * 8) * R + (r0 + tx)] = f2bf(tile[tx][ty + i * 8]);
}

__global__ void transpose_ckv(const ushort_t* __restrict__ Kp, ushort_t* __restrict__ ckvT)
{
    __shared__ ushort_t tile[32][33];
    int b = blockIdx.z;
    int s0 = blockIdx.x * 32, k0 = blockIdx.y * 32;
    int tx = threadIdx.x & 31, ty = threadIdx.x >> 5;
#pragma unroll
    for (int r = 0; r < 4; ++r)
        tile[ty + r * 8][tx] = Kp[((ll)b * 2048 + (s0 + ty + r * 8)) * 640 + (k0 + tx)];
    __syncthreads();
#pragma unroll
    for (int r = 0; r < 4; ++r)
        ckvT[((ll)b * 512 + (k0 + ty + r * 8)) * 2048 + (s0 + tx)] = tile[tx][ty + r * 8];
}

__global__ void rope_kr(ushort_t* __restrict__ Kp, const float* __restrict__ cb,
                        const float* __restrict__ sb)
{
    int idx = blockIdx.x * 256 + threadIdx.x;   // 2*2048*32
    if (idx >= 2 * 2048 * 32) return;
    int j = idx & 31, t = (idx >> 5) & 2047, b = idx >> 16;
    float c = cb[t * 32 + j], s = sb[t * 32 + j];
    ushort_t* p = Kp + ((ll)(b * 2048 + t)) * 640 + 512 + 2 * j;
    float re = bf2f(p[0]), im = bf2f(p[1]);
    p[0] = f2bf(re * c - im * s);
    p[1] = f2bf(re * s + im * c);
}

__global__ void rope_qr(const float* __restrict__ scr, const float* __restrict__ cb,
                        const float* __restrict__ sb, ushort_t* __restrict__ outq)
{
    int idx = blockIdx.x * 256 + threadIdx.x;   // 4096*512 pairs
    if (idx >= 4096 * 512) return;
    int p = idx & 511, h = p >> 5, j = p & 31;
    int row = idx >> 9;
    int t = row & 2047;
    float c = cb[t * 32 + j], s = sb[t * 32 + j];
    ll base = (ll)row * 1024 + h * 64 + 2 * j;
    float re = scr[base], im = scr[base + 1];
    outq[base]     = f2bf(re * c - im * s);
    outq[base + 1] = f2bf(re * s + im * c);
}

__global__ void pack_qtail(const ushort_t* __restrict__ qrb, ushort_t* __restrict__ Qp,
                           int b, int h0)
{
    int idx = blockIdx.x * 256 + threadIdx.x;   // 2*2048*16
    if (idx >= 2 * 2048 * 16) return;
    int c4 = idx & 15, t = (idx >> 4) & 2047, z = idx >> 15;
    const ushort4* src = (const ushort4*)(qrb + ((ll)(b * 2048 + t)) * 1024 + (h0 + z) * 64) + c4;
    ushort4* dst = (ushort4*)(Qp + ((ll)(z * 2048 + t)) * 576 + 512) + c4;
    *dst = *src;
}

__global__ __launch_bounds__(256)
void softmax_inplace(float* __restrict__ S, float scale)
{
    const int T = 2048;
    const int t = blockIdx.x, z = blockIdx.y;
    float* row = S + (ll)z * T * T + (ll)t * T;
    const int tid = threadIdx.x;
    const int n = t + 1;

    float v[8];
    float m = -1e30f;
#pragma unroll
    for (int i = 0; i < 8; ++i) {
        int s = tid + i * 256;
        v[i] = row[s] * scale;
        if (s < n) m = fmaxf(m, v[i]);
    }
    __shared__ float red[256];
    red[tid] = m; __syncthreads();
    for (int off = 128; off > 0; off >>= 1) {
        if (tid < off) red[tid] = fmaxf(red[tid], red[tid + off]);
        __syncthreads();
    }
    m = red[0]; __syncthreads();

    float lsum = 0.f;
#pragma unroll
    for (int i = 0; i < 8; ++i) {
        int s = tid + i * 256;
        if (s < n) { v[i] = __expf(v[i] - m); lsum += v[i]; }
        else v[i] = 0.f;
    }
    red[tid] = lsum; __syncthreads();
    for (int off = 128; off > 0; off >>= 1) {
        if (tid < off) red[tid] += red[tid + off];
        __syncthreads();
    }
    const float inv = 1.0f / red[0];

    ushort_t* prow = (ushort_t*)row;
#pragma unroll
    for (int i = 0; i < 8; ++i) prow[tid + i * 256] = f2bf(v[i] * inv);
}

// ---------------- host-side orchestration ----------------
static inline void gemmb(hipStream_t st, const ushort_t* A, const ushort_t* B, void* C,
                         int M, int N, int K, int a_rs, ll a_bs, int b_rs, ll b_bs,
                         int c_rs, ll c_bs, int nb, int tri = 0, int kcl = 0, int of32 = 0)
{
    dim3 g(N / TN, M / TM, nb);
    gemm_bf16<<<g, 256, 0, st>>>(A, B, C, M, N, K, a_rs, a_bs, b_rs, b_bs,
                                 c_rs, c_bs, tri, kcl, of32);
}

extern "C" void kernel_launch(void* const* d_in, const int* in_sizes, int n_in,
                              void* d_out, int out_size, void* d_ws, size_t ws_size,
                              hipStream_t stream)
{
    const float* x     = (const float*)d_in[0];
    const float* cosb  = (const float*)d_in[1];
    const float* sinb  = (const float*)d_in[2];
    const float* W_dq  = (const float*)d_in[3];
    const float* W_uq  = (const float*)d_in[4];
    const float* W_dkv = (const float*)d_in[5];
    const float* W_uk  = (const float*)d_in[6];
    const float* W_uv  = (const float*)d_in[7];
    const float* W_qr  = (const float*)d_in[8];
    const float* W_kr  = (const float*)d_in[9];
    const float* W_o   = (const float*)d_in[10];
    float* out = (float*)d_out;

    const float scale = 0.07216878364870323f; // 1/sqrt(128+64)

    // ---- workspace layout (bytes), total ~103.8 MB ----
    char* p = (char*)d_ws;
    ushort_t* xb      = (ushort_t*)p; p += 16777216;  // [4096][2048]
    ushort_t* Wkvr_b  = (ushort_t*)p; p += 2621440;   // [640][2048]
    ushort_t* Wdq_b   = (ushort_t*)p; p += 2097152;   // [512][2048]
    ushort_t* Wqr_b   = (ushort_t*)p; p += 1048576;   // [1024][512]
    ushort_t* Wuq_b   = (ushort_t*)p; p += 2097152;   // [512 l][2048 (h*128+d)]
    ushort_t* WukT_b  = (ushort_t*)p; p += 2097152;   // [16][512 k][128 d]
    ushort_t* WuvT_b  = (ushort_t*)p; p += 2097152;   // [512 k][2048 c]
    ushort_t* cq_b    = (ushort_t*)p; p += 4194304;   // [4096][512]
    ushort_t* Kp      = (ushort_t*)p; p += 5242880;   // [2][2048][640] c_kv|k_r|pad
    ushort_t* keffT_b = (ushort_t*)p; p += 8388608;   // [16][512 k][512 l]
    ushort_t* veffT_b = (ushort_t*)p; p += 2097152;   // [16][128 d][512 k]
    ushort_t* qr_b    = (ushort_t*)p; p += 8388608;   // [4096][1024]
    ushort_t* ckvT_b  = (ushort_t*)p; p += 4194304;   // [2][512 k][2048 s]
    float*    Sbuf    = (float*)p;    p += 33554432;  // [2][2048][2048] f32 (+scratch)
    ushort_t* Qp      = (ushort_t*)p; p += 4718592;   // [2][2048][576]
    ushort_t* ctx     = (ushort_t*)p; p += 4194304;   // [2][2048][512]

    // ---- bf16 conversions ----
    cvt_f32_bf16<<<8192, 256, 0, stream>>>(x, xb, 2097152);
    build_wkvr<<<1280, 256, 0, stream>>>(W_dkv, W_kr, Wkvr_b);
    cvt_f32_bf16<<<1024, 256, 0, stream>>>(W_dq, Wdq_b, 262144);
    cvt_f32_bf16<<<512, 256, 0, stream>>>(W_qr, Wqr_b, 131072);
    cvt_f32_bf16<<<1024, 256, 0, stream>>>(W_uq, Wuq_b, 262144);
    transpose_f32_bf16<<<dim3(16, 4, 16), 256, 0, stream>>>(W_uk, WukT_b, 128, 512, 65536, 65536);
    transpose_f32_bf16<<<dim3(16, 64, 1), 256, 0, stream>>>(W_uv, WuvT_b, 2048, 512, 0, 0);

    // ---- weight-only precomputes (MFMA) ----
    // keffT[h][k][l] = sum_d WukT[h][k][d] * Wuq[l][h*128+d]
    gemmb(stream, WukT_b, Wuq_b, keffT_b, 512, 512, 128,
          128, 65536, 2048, 128, 512, 262144, 16);
    // veffT[h][d][k] = sum_c Wo[h*128+d][c] * WuvT[k][c]  (Wo_b staged in Sbuf scratch)
    {
        ushort_t* Wo_b = (ushort_t*)Sbuf;
        cvt_f32_bf16<<<4096, 256, 0, stream>>>(W_o, Wo_b, 1048576);
        gemmb(stream, Wo_b, WuvT_b, veffT_b, 128, 512, 2048,
              2048, 262144, 2048, 0, 512, 65536, 16);
    }

    // ---- projections ----
    gemmb(stream, xb, Wdq_b, cq_b, 4096, 512, 2048, 2048, 0, 2048, 0, 512, 0, 1);
    gemmb(stream, xb, Wkvr_b, Kp, 4096, 640, 2048, 2048, 0, 2048, 0, 640, 0, 1);
    rope_kr<<<512, 256, 0, stream>>>(Kp, cosb, sinb);
    transpose_ckv<<<dim3(64, 16, 2), 256, 0, stream>>>(Kp, ckvT_b);
    gemmb(stream, cq_b, Wqr_b, Sbuf, 4096, 1024, 512, 512, 0, 512, 0, 1024, 0, 1, 0, 0, 1);
    rope_qr<<<8192, 256, 0, stream>>>((float*)Sbuf, cosb, sinb, qr_b);

    // ---- attention: 16 chunks of (b, 2 heads) ----
    for (int ci = 0; ci < 16; ++ci) {
        const int b = ci >> 3;
        const int h0 = (ci & 7) * 2;

        // q_eff -> Qp cols 0..511
        gemmb(stream, cq_b + (ll)b * 2048 * 512, keffT_b + (ll)h0 * 262144, Qp,
              2048, 512, 512, 512, 0, 512, 262144, 576, (ll)2048 * 576, 2);
        pack_qtail<<<256, 256, 0, stream>>>(qr_b, Qp, b, h0);

        // S = Qp · Kp^T over K=576, causal tiles only
        gemmb(stream, Qp, Kp + (ll)b * 2048 * 640, Sbuf,
              2048, 2048, 576, 576, (ll)2048 * 576, 640, 0,
              2048, (ll)2048 * 2048, 2, 1, 0, 1);

        softmax_inplace<<<dim3(2048, 2), 256, 0, stream>>>(Sbuf, scale);

        // ctx = P · c_kv  (P bf16 in-place in Sbuf rows, stride 4096 bf16)
        gemmb(stream, (ushort_t*)Sbuf, ckvT_b + (ll)b * 512 * 2048, ctx,
              2048, 512, 2048, 4096, (ll)2048 * 4096, 2048, 0,
              512, (ll)2048 * 512, 2, 0, 1);

        // y slice = ctx · veffT^T
        gemmb(stream, ctx, veffT_b + (ll)h0 * 65536, out + (ll)b * 2048 * 2048 + (ll)h0 * 128,
              2048, 128, 512, 512, (ll)2048 * 512, 512, 65536,
              2048, 128, 2, 0, 0, 1);
    }

    (void)in_sizes; (void)n_in; (void)out_size; (void)ws_size; (void)p;
}

// Round 3
// 1057.448 us; speedup vs baseline: 6.0734x; 1.9178x over previous
//
#include <hip/hip_runtime.h>
#include <hip/hip_bf16.h>
#include <math.h>

typedef long long ll;
typedef unsigned short ushort_t;
typedef __attribute__((ext_vector_type(8))) __bf16 bf16x8;
typedef __attribute__((ext_vector_type(4))) float f32x4;

// ---------------- helpers ----------------
__device__ __forceinline__ ushort_t f2bf(float f) {
    __hip_bfloat16 h = __float2bfloat16(f);   // RNE
    return *reinterpret_cast<ushort_t*>(&h);
}
__device__ __forceinline__ float bf2f(ushort_t u) {
    return __uint_as_float(((unsigned)u) << 16);
}

__device__ __forceinline__ void gld16(const void* g, void* l) {
    __builtin_amdgcn_global_load_lds(
        (const __attribute__((address_space(1))) unsigned int*)g,
        (__attribute__((address_space(3))) unsigned int*)l, 16, 0, 0);
}

// ---------------- bf16 MFMA GEMM (B^T form), TK=64, double-buffered ----------------
//   C[z][m,n] = sum_k A[z][m,k] * B[z][n,k]
// A,B bf16 K-contiguous; C fp32 or bf16, n contiguous.
// M%128==0, N%128==0, K%64==0; bases/strides 16B-aligned (in elements: mult of 8).
// LDS layout XOR-swizzled: logical 16B-unit u of row r stored at phys unit u^(r&7).
// Staging via global_load_lds (wave-uniform dest + lane*16): lane l of a wave
// covers row (l>>3) of an 8-row segment, phys unit (l&7) -> fetches logical
// unit (l&7)^(l>>3). ds_read side: 2-way bank aliasing max (free, m136).
#define TM 128
#define TN 128
#define TK 64

__global__ __launch_bounds__(256)
void gemm_bf16(const ushort_t* __restrict__ Ab, const ushort_t* __restrict__ Bb,
               void* __restrict__ Cb,
               int M, int N, int K,
               int a_rs, ll a_bs, int b_rs, ll b_bs,
               int c_rs, ll c_bs,
               int tri_skip, int k_clamp, int out_f32)
{
    const int m0 = blockIdx.y * TM;
    const int n0 = blockIdx.x * TN;
    if (tri_skip && n0 >= m0 + TM) return;   // fully above causal diagonal

    const ushort_t* A = Ab + (ll)blockIdx.z * a_bs;
    const ushort_t* B = Bb + (ll)blockIdx.z * b_bs;

    int Keff = K;
    if (k_clamp) { int kl = m0 + TM; if (kl < Keff) Keff = kl; }

    __shared__ ushort_t As[2][TM][TK];   // 32 KB
    __shared__ ushort_t Bs[2][TN][TK];   // 32 KB

    const int tid  = threadIdx.x;
    const int w    = tid >> 6;
    const int l    = tid & 63;
    const int lo16 = l & 15;
    const int quad = l >> 4;
    const int wm0  = (w & 1) * 64;
    const int wn0  = (w >> 1) * 64;

    const int srow  = l >> 3;            // 0..7 row within 8-row segment
    const int sunit = (l & 7) ^ srow;    // logical 16B unit this lane fetches

    f32x4 acc[4][4];
    const f32x4 zero = {0.f, 0.f, 0.f, 0.f};
#pragma unroll
    for (int mi = 0; mi < 4; ++mi)
#pragma unroll
        for (int nj = 0; nj < 4; ++nj) acc[mi][nj] = zero;

    const int nIter = Keff / TK;

    // stage buffer 0
#pragma unroll
    for (int i = 0; i < 4; ++i) {
        const int rr = w * 32 + i * 8;
        gld16(A + (ll)(m0 + rr + srow) * a_rs + (0 + sunit * 8), &As[0][rr][0]);
    }
#pragma unroll
    for (int i = 0; i < 4; ++i) {
        const int rr = w * 32 + i * 8;
        gld16(B + (ll)(n0 + rr + srow) * b_rs + (0 + sunit * 8), &Bs[0][rr][0]);
    }

    int buf = 0;
    for (int it = 0; it < nIter; ++it) {
        __syncthreads();                    // drains staging of `buf`
        if (it + 1 < nIter) {               // prefetch next into other buffer,
            const int k0 = (it + 1) * TK;   // in flight during compute below
            const int nb = buf ^ 1;
#pragma unroll
            for (int i = 0; i < 4; ++i) {
                const int rr = w * 32 + i * 8;
                gld16(A + (ll)(m0 + rr + srow) * a_rs + (k0 + sunit * 8), &As[nb][rr][0]);
            }
#pragma unroll
            for (int i = 0; i < 4; ++i) {
                const int rr = w * 32 + i * 8;
                gld16(B + (ll)(n0 + rr + srow) * b_rs + (k0 + sunit * 8), &Bs[nb][rr][0]);
            }
        }
#pragma unroll
        for (int h = 0; h < 2; ++h) {
            const int phys = (h * 4 + quad) ^ (lo16 & 7);
            bf16x8 af[4], bfr[4];
#pragma unroll
            for (int mi = 0; mi < 4; ++mi)
                af[mi] = *(const bf16x8*)&As[buf][wm0 + mi * 16 + lo16][phys * 8];
#pragma unroll
            for (int nj = 0; nj < 4; ++nj)
                bfr[nj] = *(const bf16x8*)&Bs[buf][wn0 + nj * 16 + lo16][phys * 8];
#pragma unroll
            for (int mi = 0; mi < 4; ++mi)
#pragma unroll
                for (int nj = 0; nj < 4; ++nj)
                    acc[mi][nj] = __builtin_amdgcn_mfma_f32_16x16x32_bf16(
                        af[mi], bfr[nj], acc[mi][nj], 0, 0, 0);
        }
        buf ^= 1;
    }

    // epilogue: C row = quad*4 + reg, col = lane&15 (verified m89/m91 + round 1)
    if (out_f32) {
        float* C = (float*)Cb + (ll)blockIdx.z * c_bs;
#pragma unroll
        for (int mi = 0; mi < 4; ++mi)
#pragma unroll
            for (int r = 0; r < 4; ++r) {
                const ll row = m0 + wm0 + mi * 16 + quad * 4 + r;
                float* cr = C + row * (ll)c_rs + (n0 + wn0 + lo16);
#pragma unroll
                for (int nj = 0; nj < 4; ++nj) cr[nj * 16] = acc[mi][nj][r];
            }
    } else {
        ushort_t* C = (ushort_t*)Cb + (ll)blockIdx.z * c_bs;
#pragma unroll
        for (int mi = 0; mi < 4; ++mi)
#pragma unroll
            for (int r = 0; r < 4; ++r) {
                const ll row = m0 + wm0 + mi * 16 + quad * 4 + r;
                ushort_t* cr = C + row * (ll)c_rs + (n0 + wn0 + lo16);
#pragma unroll
                for (int nj = 0; nj < 4; ++nj) cr[nj * 16] = f2bf(acc[mi][nj][r]);
            }
    }
}

// ---------------- conversion / layout kernels ----------------
__global__ void cvt_f32_bf16(const float* __restrict__ in, ushort_t* __restrict__ out, ll n4)
{
    ll i = (ll)blockIdx.x * 256 + threadIdx.x;
    if (i >= n4) return;
    float4 v = *(const float4*)(in + i * 4);
    ushort4 u;
    u.x = f2bf(v.x); u.y = f2bf(v.y); u.z = f2bf(v.z); u.w = f2bf(v.w);
    *(ushort4*)(out + i * 4) = u;
}

// Wkvr [640][2048]: rows 0..511 = W_dkv, 512..575 = W_kr, 576..639 = 0
__global__ void build_wkvr(const float* __restrict__ Wdkv, const float* __restrict__ Wkr,
                           ushort_t* __restrict__ out)
{
    ll i4 = ((ll)blockIdx.x * 256 + threadIdx.x) * 4;
    if (i4 >= (ll)640 * 2048) return;
    int row = (int)(i4 >> 11);
    int col = (int)(i4 & 2047);
    float4 v;
    if (row < 512)      v = *(const float4*)(Wdkv + (ll)row * 2048 + col);
    else if (row < 576) v = *(const float4*)(Wkr + (ll)(row - 512) * 2048 + col);
    else                v = make_float4(0.f, 0.f, 0.f, 0.f);
    ushort4 u;
    u.x = f2bf(v.x); u.y = f2bf(v.y); u.z = f2bf(v.z); u.w = f2bf(v.w);
    *(ushort4*)(out + i4) = u;
}

__global__ void transpose_f32_bf16(const float* __restrict__ in, ushort_t* __restrict__ out,
                                   int R, int C, ll in_bs, ll out_bs)
{
    __shared__ float tile[32][33];
    const float* I = in + (ll)blockIdx.z * in_bs;
    ushort_t*    O = out + (ll)blockIdx.z * out_bs;
    int r0 = blockIdx.y * 32, c0 = blockIdx.x * 32;
    int tx = threadIdx.x & 31, ty = threadIdx.x >> 5;
#pragma unroll
    for (int i = 0; i < 4; ++i)
        tile[ty + i * 8][tx] = I[(ll)(r0 + ty + i * 8) * C + (c0 + tx)];
    __syncthreads();
#pragma unroll
    for (int i = 0; i < 4; ++i)
        O[(ll)(c0 + ty + i * 8) * R + (r0 + tx)] = f2bf(tile[tx][ty + i * 8]);
}

// rope on Kp tail cols [512..576) in place (bf16)
__global__ void rope_kr(ushort_t* __restrict__ Kp, const float* __restrict__ cb,
                        const float* __restrict__ sb)
{
    int idx = blockIdx.x * 256 + threadIdx.x;   // 2*2048*32 = 131072
    if (idx >= 2 * 2048 * 32) return;
    int j = idx & 31, t = (idx >> 5) & 2047, b = idx >> 16;
    float c = cb[t * 32 + j], s = sb[t * 32 + j];
    ushort_t* p = Kp + ((ll)(b * 2048 + t)) * 640 + 512 + 2 * j;
    float re = bf2f(p[0]), im = bf2f(p[1]);
    p[0] = f2bf(re * c - im * s);
    p[1] = f2bf(re * s + im * c);
}

// rope on q_r: read f32 scratch [4096][1024], write bf16 same layout
__global__ void rope_qr(const float* __restrict__ scr, const float* __restrict__ cb,
                        const float* __restrict__ sb, ushort_t* __restrict__ outq)
{
    int idx = blockIdx.x * 256 + threadIdx.x;   // 4096*512 pairs
    if (idx >= 4096 * 512) return;
    int p = idx & 511, h = p >> 5, j = p & 31;
    int row = idx >> 9;
    int t = row & 2047;
    float c = cb[t * 32 + j], s = sb[t * 32 + j];
    ll base = (ll)row * 1024 + h * 64 + 2 * j;
    float re = scr[base], im = scr[base + 1];
    outq[base]     = f2bf(re * c - im * s);
    outq[base + 1] = f2bf(re * s + im * c);
}

// copy rope'd q_r head slices (4 heads) into Qp tail cols [512..576)
__global__ void pack_qtail(const ushort_t* __restrict__ qrb, ushort_t* __restrict__ Qp,
                           int b, int h0)
{
    int idx = blockIdx.x * 256 + threadIdx.x;   // 4*2048*16 = 131072
    if (idx >= 4 * 2048 * 16) return;
    int c4 = idx & 15, t = (idx >> 4) & 2047, z = idx >> 15;
    const ushort4* src = (const ushort4*)(qrb + ((ll)(b * 2048 + t)) * 1024 + (h0 + z) * 64) + c4;
    ushort4* dst = (ushort4*)(Qp + ((ll)(z * 2048 + t)) * 576 + 512) + c4;
    *dst = *src;
}

// causal softmax on bf16 S in place: row t of pair z; reads s<t+1, writes P
// for s<t+1 and zeros up to the 128-aligned boundary npad = ((t>>7)+1)*128
// (exactly the PV GEMM's k_clamp read range). Cols >= npad never touched.
__global__ __launch_bounds__(256)
void softmax_bf16(ushort_t* __restrict__ S, float scale)
{
    const int T = 2048;
    const int t = blockIdx.x, z = blockIdx.y;
    ushort_t* row = S + ((ll)z * T + t) * T;
    const int tid = threadIdx.x;
    const int n = t + 1;
    const int npad = ((t >> 7) + 1) << 7;

    float v[8];
    float m = -1e30f;
#pragma unroll
    for (int i = 0; i < 8; ++i) {
        int s = tid + i * 256;
        if (s < n) { v[i] = bf2f(row[s]) * scale; m = fmaxf(m, v[i]); }
        else v[i] = -1e30f;
    }
    __shared__ float red[256];
    red[tid] = m; __syncthreads();
    for (int off = 128; off > 0; off >>= 1) {
        if (tid < off) red[tid] = fmaxf(red[tid], red[tid + off]);
        __syncthreads();
    }
    m = red[0]; __syncthreads();

    float lsum = 0.f;
#pragma unroll
    for (int i = 0; i < 8; ++i) {
        int s = tid + i * 256;
        if (s < n) { v[i] = __expf(v[i] - m); lsum += v[i]; }
        else v[i] = 0.f;
    }
    red[tid] = lsum; __syncthreads();
    for (int off = 128; off > 0; off >>= 1) {
        if (tid < off) red[tid] += red[tid + off];
        __syncthreads();
    }
    const float inv = 1.0f / red[0];

#pragma unroll
    for (int i = 0; i < 8; ++i) {
        int s = tid + i * 256;
        if (s < n)         row[s] = f2bf(v[i] * inv);
        else if (s < npad) row[s] = 0;
    }
}

// ---------------- host-side orchestration ----------------
static inline void gemmb(hipStream_t st, const ushort_t* A, const ushort_t* B, void* C,
                         int M, int N, int K, int a_rs, ll a_bs, int b_rs, ll b_bs,
                         int c_rs, ll c_bs, int nb, int tri = 0, int kcl = 0, int of32 = 0)
{
    dim3 g(N / TN, M / TM, nb);
    gemm_bf16<<<g, 256, 0, st>>>(A, B, C, M, N, K, a_rs, a_bs, b_rs, b_bs,
                                 c_rs, c_bs, tri, kcl, of32);
}

extern "C" void kernel_launch(void* const* d_in, const int* in_sizes, int n_in,
                              void* d_out, int out_size, void* d_ws, size_t ws_size,
                              hipStream_t stream)
{
    const float* x     = (const float*)d_in[0];
    const float* cosb  = (const float*)d_in[1];
    const float* sinb  = (const float*)d_in[2];
    const float* W_dq  = (const float*)d_in[3];
    const float* W_uq  = (const float*)d_in[4];
    const float* W_dkv = (const float*)d_in[5];
    const float* W_uk  = (const float*)d_in[6];
    const float* W_uv  = (const float*)d_in[7];
    const float* W_qr  = (const float*)d_in[8];
    const float* W_kr  = (const float*)d_in[9];
    const float* W_o   = (const float*)d_in[10];
    float* out = (float*)d_out;

    const float scale = 0.07216878364870323f; // 1/sqrt(128+64)

    // ---- workspace layout (bytes), total ~102.2 MB ----
    char* base = (char*)d_ws;
    ushort_t* Wkvr_b  = (ushort_t*)(base + 0);         // [640][2048]        2.62 MB
    ushort_t* Wdq_b   = (ushort_t*)(base + 2621440);   // [512][2048]        2.10
    ushort_t* Wqr_b   = (ushort_t*)(base + 4718592);   // [1024][512]        1.05
    ushort_t* Wuq_b   = (ushort_t*)(base + 5767168);   // [512 l][2048 hd]   2.10
    ushort_t* WukT_b  = (ushort_t*)(base + 7864320);   // [16][512 k][128 d] 2.10
    ushort_t* WuvT_b  = (ushort_t*)(base + 9961472);   // [512 k][2048 c]    2.10
    ushort_t* cq_b    = (ushort_t*)(base + 12058624);  // [4096][512]        4.19
    ushort_t* Kp      = (ushort_t*)(base + 16252928);  // [2][2048][640]     5.24
    ushort_t* keffT_b = (ushort_t*)(base + 21495808);  // [16][512 k][512 l] 8.39
    ushort_t* veffT_b = (ushort_t*)(base + 29884416);  // [16][128 d][512 k] 2.10
    ushort_t* qr_b    = (ushort_t*)(base + 31981568);  // [4096][1024]       8.39
    ushort_t* VT_all  = (ushort_t*)(base + 40370176);  // [2][16][128 d][2048 s] 16.78
    char*     CR      = base + 57147392;               // chunk region, 43.0 MB
    // CR overlays (in time order):
    ushort_t* xb      = (ushort_t*)(CR + 0);           // [4096][2048]       16.78
    ushort_t* Wo_b    = (ushort_t*)(CR + 16777216);    // [2048][2048]       8.39
    float*    qscr    = (float*)(CR + 0);              // [4096][1024] f32   16.78 (after xb dead)
    ushort_t* Qp      = (ushort_t*)(CR + 0);           // [4][2048][576]     9.44  (chunk phase)
    ushort_t* Sb      = (ushort_t*)(CR + 9437184);     // [4][2048][2048]    33.55 (chunk phase)

    // ---- bf16 conversions ----
    cvt_f32_bf16<<<8192, 256, 0, stream>>>(x, xb, 2097152);
    build_wkvr<<<1280, 256, 0, stream>>>(W_dkv, W_kr, Wkvr_b);
    cvt_f32_bf16<<<1024, 256, 0, stream>>>(W_dq, Wdq_b, 262144);
    cvt_f32_bf16<<<512, 256, 0, stream>>>(W_qr, Wqr_b, 131072);
    cvt_f32_bf16<<<1024, 256, 0, stream>>>(W_uq, Wuq_b, 262144);
    cvt_f32_bf16<<<4096, 256, 0, stream>>>(W_o, Wo_b, 1048576);
    transpose_f32_bf16<<<dim3(16, 4, 16), 256, 0, stream>>>(W_uk, WukT_b, 128, 512, 65536, 65536);
    transpose_f32_bf16<<<dim3(16, 64, 1), 256, 0, stream>>>(W_uv, WuvT_b, 2048, 512, 0, 0);

    // ---- weight-only precomputes ----
    // keffT[h][k][l] = sum_d WukT[h][k][d] * Wuq[l][h*128+d]
    gemmb(stream, WukT_b, Wuq_b, keffT_b, 512, 512, 128,
          128, 65536, 2048, 128, 512, 262144, 16);
    // veffT[h][d][k] = sum_c Wo[h*128+d][c] * WuvT[k][c]
    gemmb(stream, Wo_b, WuvT_b, veffT_b, 128, 512, 2048,
          2048, 262144, 2048, 0, 512, 65536, 16);

    // ---- projections (use xb; xb dead after these) ----
    gemmb(stream, xb, Wdq_b, cq_b, 4096, 512, 2048, 2048, 0, 2048, 0, 512, 0, 1);
    gemmb(stream, xb, Wkvr_b, Kp, 4096, 640, 2048, 2048, 0, 2048, 0, 640, 0, 1);
    rope_kr<<<512, 256, 0, stream>>>(Kp, cosb, sinb);

    // V^T precompute: VT[b][h][d][s] = sum_k veffT[h][d][k] * c_kv[b][s][k]
    for (int b = 0; b < 2; ++b)
        gemmb(stream, veffT_b, Kp + (ll)b * 2048 * 640, VT_all + (ll)b * 16 * 262144,
              128, 2048, 512, 512, 65536, 640, 0, 2048, 262144, 16);

    // q_r raw = c_q · Wqr^T -> f32 scratch (overwrites dead xb), then rope -> qr_b
    gemmb(stream, cq_b, Wqr_b, qscr, 4096, 1024, 512, 512, 0, 512, 0, 1024, 0, 1, 0, 0, 1);
    rope_qr<<<8192, 256, 0, stream>>>(qscr, cosb, sinb, qr_b);

    // ---- attention: 8 chunks of (b, 4 heads) ----
    for (int ci = 0; ci < 8; ++ci) {
        const int b = ci >> 2;
        const int h0 = (ci & 3) * 4;

        // q_eff -> Qp cols 0..511 (z = 4 heads)
        gemmb(stream, cq_b + (ll)b * 2048 * 512, keffT_b + (ll)h0 * 262144, Qp,
              2048, 512, 512, 512, 0, 512, 262144, 576, (ll)2048 * 576, 4);
        pack_qtail<<<512, 256, 0, stream>>>(qr_b, Qp, b, h0);

        // S = Qp · Kp^T over K=576, causal tiles only, bf16 out
        gemmb(stream, Qp, Kp + (ll)b * 2048 * 640, Sb,
              2048, 2048, 576, 576, (ll)2048 * 576, 640, 0,
              2048, (ll)2048 * 2048, 4, /*tri*/1);

        softmax_bf16<<<dim3(2048, 4), 256, 0, stream>>>(Sb, scale);

        // y slice = P · V^T  (K = s, clamped causally), fp32 direct to out
        gemmb(stream, Sb, VT_all + ((ll)b * 16 + h0) * 262144,
              out + (ll)b * 2048 * 2048 + (ll)h0 * 128,
              2048, 128, 2048, 2048, (ll)2048 * 2048, 2048, 262144,
              2048, 128, 4, 0, /*kcl*/1, /*f32*/1);
    }

    (void)in_sizes; (void)n_in; (void)out_size; (void)ws_size;
}

// Round 5
// 622.873 us; speedup vs baseline: 10.3108x; 1.6977x over previous
//
#include <hip/hip_runtime.h>
#include <hip/hip_bf16.h>
#include <math.h>

typedef long long ll;
typedef unsigned short ushort_t;
typedef __attribute__((ext_vector_type(8))) __bf16 bf16x8;
typedef __attribute__((ext_vector_type(4))) float f32x4;

// ---------------- helpers ----------------
__device__ __forceinline__ ushort_t f2bf(float f) {
    __hip_bfloat16 h = __float2bfloat16(f);
    return *reinterpret_cast<ushort_t*>(&h);
}
__device__ __forceinline__ float bf2f(ushort_t u) {
    return __uint_as_float(((unsigned)u) << 16);
}
// global->LDS DMA: lds dest must be wave-uniform; lane i deposits at dest + i*16
__device__ __forceinline__ void stage16(const void* g_lane, void* lds_uniform) {
    __builtin_amdgcn_global_load_lds(
        (const __attribute__((address_space(1))) unsigned int*)g_lane,
        (__attribute__((address_space(3))) unsigned int*)lds_uniform, 16, 0, 0);
}

// ---------------- bf16 MFMA GEMM (B^T form), TK=64, double-buffered ----------------
//   C[z][m,n] = sum_k A[z][m,k] * B[z][n,k];  z1 = z/Z2, z2 = z%Z2
// A,B bf16 K-contiguous; C fp32 or bf16, n contiguous. M%128==0, N%128==0, K%64==0.
#define TM 128
#define TN 128
#define TK 64

__global__ __launch_bounds__(256)
void gemm_bf16(const ushort_t* __restrict__ Ab, const ushort_t* __restrict__ Bb,
               void* __restrict__ Cb,
               int M, int N, int K,
               int a_rs, int b_rs, int c_rs, int Z2,
               ll a_bs1, ll a_bs2, ll b_bs1, ll b_bs2, ll c_bs1, ll c_bs2,
               int out_f32)
{
    const int m0 = blockIdx.y * TM;
    const int n0 = blockIdx.x * TN;
    const int z1 = blockIdx.z / Z2, z2 = blockIdx.z % Z2;

    const ushort_t* A = Ab + z1 * a_bs1 + z2 * a_bs2;
    const ushort_t* B = Bb + z1 * b_bs1 + z2 * b_bs2;

    __shared__ ushort_t As[2][TM][TK];
    __shared__ ushort_t Bs[2][TN][TK];

    const int tid  = threadIdx.x;
    const int w    = tid >> 6;
    const int l    = tid & 63;
    const int lo16 = l & 15;
    const int quad = l >> 4;
    const int wm0  = (w & 1) * 64;
    const int wn0  = (w >> 1) * 64;

    const int srow  = l >> 3;            // row within 8-row segment
    const int sunit = (l & 7) ^ srow;    // logical 16B unit this lane fetches

    f32x4 acc[4][4];
    const f32x4 zero = {0.f, 0.f, 0.f, 0.f};
#pragma unroll
    for (int mi = 0; mi < 4; ++mi)
#pragma unroll
        for (int nj = 0; nj < 4; ++nj) acc[mi][nj] = zero;

    const int nIter = K / TK;

#pragma unroll
    for (int i = 0; i < 4; ++i) {
        const int rr = w * 32 + i * 8;
        stage16(A + (ll)(m0 + rr + srow) * a_rs + sunit * 8, &As[0][rr][0]);
        stage16(B + (ll)(n0 + rr + srow) * b_rs + sunit * 8, &Bs[0][rr][0]);
    }

    int buf = 0;
    for (int it = 0; it < nIter; ++it) {
        __syncthreads();
        if (it + 1 < nIter) {
            const int k0 = (it + 1) * TK;
            const int nb = buf ^ 1;
#pragma unroll
            for (int i = 0; i < 4; ++i) {
                const int rr = w * 32 + i * 8;
                stage16(A + (ll)(m0 + rr + srow) * a_rs + (k0 + sunit * 8), &As[nb][rr][0]);
                stage16(B + (ll)(n0 + rr + srow) * b_rs + (k0 + sunit * 8), &Bs[nb][rr][0]);
            }
        }
#pragma unroll
        for (int h = 0; h < 2; ++h) {
            const int phys = (h * 4 + quad) ^ (lo16 & 7);
            bf16x8 af[4], bfr[4];
#pragma unroll
            for (int mi = 0; mi < 4; ++mi)
                af[mi] = *(const bf16x8*)&As[buf][wm0 + mi * 16 + lo16][phys * 8];
#pragma unroll
            for (int nj = 0; nj < 4; ++nj)
                bfr[nj] = *(const bf16x8*)&Bs[buf][wn0 + nj * 16 + lo16][phys * 8];
#pragma unroll
            for (int mi = 0; mi < 4; ++mi)
#pragma unroll
                for (int nj = 0; nj < 4; ++nj)
                    acc[mi][nj] = __builtin_amdgcn_mfma_f32_16x16x32_bf16(
                        af[mi], bfr[nj], acc[mi][nj], 0, 0, 0);
        }
        buf ^= 1;
    }

    if (out_f32) {
        float* C = (float*)Cb + z1 * c_bs1 + z2 * c_bs2;
#pragma unroll
        for (int mi = 0; mi < 4; ++mi)
#pragma unroll
            for (int r = 0; r < 4; ++r) {
                const ll row = m0 + wm0 + mi * 16 + quad * 4 + r;
                float* cr = C + row * (ll)c_rs + (n0 + wn0 + lo16);
#pragma unroll
                for (int nj = 0; nj < 4; ++nj) cr[nj * 16] = acc[mi][nj][r];
            }
    } else {
        ushort_t* C = (ushort_t*)Cb + z1 * c_bs1 + z2 * c_bs2;
#pragma unroll
        for (int mi = 0; mi < 4; ++mi)
#pragma unroll
            for (int r = 0; r < 4; ++r) {
                const ll row = m0 + wm0 + mi * 16 + quad * 4 + r;
                ushort_t* cr = C + row * (ll)c_rs + (n0 + wn0 + lo16);
#pragma unroll
                for (int nj = 0; nj < 4; ++nj) cr[nj * 16] = f2bf(acc[mi][nj][r]);
            }
    }
}

// ---------------- fused flash-MLA attention ----------------
// Grid (32 qtiles, 16 h, 2 b), 256 thr. qt reversed so longest blocks launch first.
// Per block: build Q[64][576] A-frags in regs (Qeff = q_up_tile . WukT^T, + rope'd
// q_r from global), then stream 32-wide K/V tiles: S=QK^T (fp32), online softmax,
// O += P.V. Writes fp32 out directly.
__global__ __launch_bounds__(256, 2)
void flash_mla(const ushort_t* __restrict__ q_up,  // [2][2048][2048]
               const ushort_t* __restrict__ qr,    // [2][2048][1024]
               const ushort_t* __restrict__ WukT,  // [16][512][128]
               const ushort_t* __restrict__ Kp,    // [2][2048][640]
               const ushort_t* __restrict__ VT,    // [2][16][128][2048]
               float* __restrict__ out,            // [2][2048][2048]
               float scale)
{
    const int qt = 31 - blockIdx.x;
    const int h  = blockIdx.y;
    const int b  = blockIdx.z;
    const int t0 = qt * 64;

    __shared__ char smem[54272];
    ushort_t* Ks = (ushort_t*)smem;             // [32][576] swizzled (36864 B)
    ushort_t* Vs = (ushort_t*)(smem + 36864);   // [128][32] swizzled (8192 B)
    ushort_t* Q3 = (ushort_t*)(smem + 45056);   // Qstage [4][16][72] / Ps [4][16][40]
    ushort_t* Aq = (ushort_t*)smem;             // build alias [64][128]
    ushort_t* Bw = (ushort_t*)(smem + 16384);   // build alias [64][128]

    const int tid  = threadIdx.x;
    const int w    = tid >> 6;
    const int l    = tid & 63;
    const int lo16 = l & 15;
    const int quad = l >> 4;

    // ---- phase 1: build Q A-frags qa[0..17] (k-tiles of 32 over 576) ----
    bf16x8 qa[18];

    // stage Aq[r][d] = q_up[b][t0+r][h*128+d], 64x128, swizzle u^(r&15)
#pragma unroll
    for (int i = 0; i < 4; ++i) {
        int p = w * 256 + i * 64 + l;
        int r = p >> 4, u = p & 15, ul = u ^ (r & 15);
        stage16(q_up + ((ll)(b * 2048 + t0 + r)) * 2048 + h * 128 + ul * 8,
                (char*)Aq + (ll)(w * 256 + i * 64) * 16);
    }
    // stage Bw chunk 0: WukT[h][0..64][128]
#pragma unroll
    for (int i = 0; i < 4; ++i) {
        int p = w * 256 + i * 64 + l;
        int r = p >> 4, u = p & 15, ul = u ^ (r & 15);
        stage16(WukT + ((ll)h * 512 + r) * 128 + ul * 8,
                (char*)Bw + (ll)(w * 256 + i * 64) * 16);
    }
    __syncthreads();

    bf16x8 ab[4];
#pragma unroll
    for (int kd = 0; kd < 4; ++kd)
        ab[kd] = *(const bf16x8*)(Aq + (16 * w + lo16) * 128 + (((kd * 4 + quad) ^ lo16) & 15) * 8);

    for (int kc = 0; kc < 8; ++kc) {
#pragma unroll
        for (int nt = 0; nt < 4; ++nt) {
            f32x4 c = {0.f, 0.f, 0.f, 0.f};
#pragma unroll
            for (int kd = 0; kd < 4; ++kd) {
                bf16x8 bb = *(const bf16x8*)(Bw + (nt * 16 + lo16) * 128 +
                                             (((kd * 4 + quad) ^ lo16) & 15) * 8);
                c = __builtin_amdgcn_mfma_f32_16x16x32_bf16(ab[kd], bb, c, 0, 0, 0);
            }
#pragma unroll
            for (int r = 0; r < 4; ++r)
                Q3[(w * 16 + quad * 4 + r) * 72 + nt * 16 + lo16] = f2bf(c[r]);
        }
        // read back this chunk's 2 A k-tiles (wave-private region)
#pragma unroll
        for (int kd2 = 0; kd2 < 2; ++kd2)
            qa[kc * 2 + kd2] = *(const bf16x8*)(Q3 + (w * 16 + lo16) * 72 + kd2 * 32 + quad * 8);

        if (kc < 7) {
            __syncthreads();
#pragma unroll
            for (int i = 0; i < 4; ++i) {
                int p = w * 256 + i * 64 + l;
                int r = p >> 4, u = p & 15, ul = u ^ (r & 15);
                stage16(WukT + ((ll)h * 512 + (kc + 1) * 64 + r) * 128 + ul * 8,
                        (char*)Bw + (ll)(w * 256 + i * 64) * 16);
            }
            __syncthreads();
        }
    }
    // rope tiles 16,17 straight from global
#pragma unroll
    for (int kt = 16; kt < 18; ++kt)
        qa[kt] = *(const bf16x8*)(qr + ((ll)(b * 2048 + t0 + 16 * w + lo16)) * 1024 +
                                  h * 64 + (kt - 16) * 32 + quad * 8);

    // ---- phase 2: K/V loop ----
    f32x4 oacc[8];
    const f32x4 zero = {0.f, 0.f, 0.f, 0.f};
#pragma unroll
    for (int dt = 0; dt < 8; ++dt) oacc[dt] = zero;
    float mrow[4], lrow[4];
#pragma unroll
    for (int r = 0; r < 4; ++r) { mrow[r] = -3.0e38f; lrow[r] = 0.f; }

    const int nst = 2 * qt + 2;
    for (int st = 0; st < nst; ++st) {
        const int s0 = st * 32;
        __syncthreads();
        // stage Ks[32][576]: per-wave slab rows 8w..8w+8 (576 units), swizzle u^(r&7)
#pragma unroll
        for (int i = 0; i < 9; ++i) {
            int p = i * 64 + l;                 // 0..575 within slab
            int r = 8 * w + p / 72, u = p % 72, ul = u ^ (r & 7);
            stage16(Kp + ((ll)(b * 2048 + s0 + r)) * 640 + ul * 8,
                    (char*)Ks + (ll)(w * 576 + i * 64) * 16);
        }
        // stage Vs[128][32]: 512 units, swizzle u^(r&3)
#pragma unroll
        for (int i = 0; i < 2; ++i) {
            int p = w * 128 + i * 64 + l;
            int r = p >> 2, u = p & 3, ul = u ^ (r & 3);
            stage16(VT + (((ll)(b * 16 + h)) * 128 + r) * 2048 + s0 + ul * 8,
                    (char*)Vs + (ll)(w * 128 + i * 64) * 16);
        }
        __syncthreads();

        // S = Q.K^T (fp32), 16x32 per wave
        f32x4 sc[2];
        sc[0] = zero; sc[1] = zero;
#pragma unroll
        for (int kt = 0; kt < 18; ++kt) {
#pragma unroll
            for (int nt = 0; nt < 2; ++nt) {
                int phys = (kt * 4 + quad) ^ (lo16 & 7);
                bf16x8 kb = *(const bf16x8*)(Ks + (nt * 16 + lo16) * 576 + phys * 8);
                sc[nt] = __builtin_amdgcn_mfma_f32_16x16x32_bf16(qa[kt], kb, sc[nt], 0, 0, 0);
            }
        }
        // scale, then causal mask (only diagonal tiles st >= 2*qt can cross)
        const int rbase = 16 * w + quad * 4;    // row - t0
#pragma unroll
        for (int nt = 0; nt < 2; ++nt)
#pragma unroll
            for (int r = 0; r < 4; ++r) sc[nt][r] *= scale;
        if (st >= 2 * qt) {
#pragma unroll
            for (int nt = 0; nt < 2; ++nt)
#pragma unroll
                for (int r = 0; r < 4; ++r)
                    if ((s0 + nt * 16 + lo16) > (t0 + rbase + r))   // s_glob > t_glob
                        sc[nt][r] = -INFINITY;
        }

        // online softmax per row (row spans the 16 lanes of each quad group)
        float alpha[4];
#pragma unroll
        for (int r = 0; r < 4; ++r) {
            float tm = fmaxf(sc[0][r], sc[1][r]);
#pragma unroll
            for (int off = 1; off <= 8; off <<= 1)
                tm = fmaxf(tm, __shfl_xor(tm, off, 64));
            float mnew = fmaxf(mrow[r], tm);
            alpha[r] = __expf(mrow[r] - mnew);
            mrow[r] = mnew;
            sc[0][r] = __expf(sc[0][r] - mnew);
            sc[1][r] = __expf(sc[1][r] - mnew);
            float rs = sc[0][r] + sc[1][r];
#pragma unroll
            for (int off = 1; off <= 8; off <<= 1)
                rs += __shfl_xor(rs, off, 64);
            lrow[r] = lrow[r] * alpha[r] + rs;
        }
        // O *= alpha
#pragma unroll
        for (int dt = 0; dt < 8; ++dt)
#pragma unroll
            for (int r = 0; r < 4; ++r) oacc[dt][r] *= alpha[r];

        // P -> bf16 -> wave-private LDS -> A-frag
#pragma unroll
        for (int nt = 0; nt < 2; ++nt)
#pragma unroll
            for (int r = 0; r < 4; ++r)
                Q3[w * 640 + (quad * 4 + r) * 40 + nt * 16 + lo16] = f2bf(sc[nt][r]);
        bf16x8 pf = *(const bf16x8*)(Q3 + w * 640 + lo16 * 40 + quad * 8);

        // O += P.V
#pragma unroll
        for (int dt = 0; dt < 8; ++dt) {
            int phys = quad ^ (lo16 & 3);
            bf16x8 vb = *(const bf16x8*)(Vs + (dt * 16 + lo16) * 32 + phys * 8);
            oacc[dt] = __builtin_amdgcn_mfma_f32_16x16x32_bf16(pf, vb, oacc[dt], 0, 0, 0);
        }
    }

    // ---- epilogue: y = O / l ----
#pragma unroll
    for (int r = 0; r < 4; ++r) {
        const float inv = 1.0f / lrow[r];
        const ll row = (ll)(b * 2048 + t0 + 16 * w + quad * 4 + r);
#pragma unroll
        for (int dt = 0; dt < 8; ++dt)
            out[row * 2048 + h * 128 + dt * 16 + lo16] = oacc[dt][r] * inv;
    }
}

// ---------------- conversion / layout kernels ----------------
__global__ void cvt_f32_bf16(const float* __restrict__ in, ushort_t* __restrict__ out, ll n4)
{
    ll i = (ll)blockIdx.x * 256 + threadIdx.x;
    if (i >= n4) return;
    float4 v = *(const float4*)(in + i * 4);
    ushort4 u;
    u.x = f2bf(v.x); u.y = f2bf(v.y); u.z = f2bf(v.z); u.w = f2bf(v.w);
    *(ushort4*)(out + i * 4) = u;
}

__global__ void build_wkvr(const float* __restrict__ Wdkv, const float* __restrict__ Wkr,
                           ushort_t* __restrict__ out)
{
    ll i4 = ((ll)blockIdx.x * 256 + threadIdx.x) * 4;
    if (i4 >= (ll)640 * 2048) return;
    int row = (int)(i4 >> 11);
    int col = (int)(i4 & 2047);
    float4 v;
    if (row < 512)      v = *(const float4*)(Wdkv + (ll)row * 2048 + col);
    else if (row < 576) v = *(const float4*)(Wkr + (ll)(row - 512) * 2048 + col);
    else                v = make_float4(0.f, 0.f, 0.f, 0.f);
    ushort4 u;
    u.x = f2bf(v.x); u.y = f2bf(v.y); u.z = f2bf(v.z); u.w = f2bf(v.w);
    *(ushort4*)(out + i4) = u;
}

__global__ void transpose_f32_bf16(const float* __restrict__ in, ushort_t* __restrict__ out,
                                   int R, int C, ll in_bs, ll out_bs)
{
    __shared__ float tile[32][33];
    const float* I = in + (ll)blockIdx.z * in_bs;
    ushort_t*    O = out + (ll)blockIdx.z * out_bs;
    int r0 = blockIdx.y * 32, c0 = blockIdx.x * 32;
    int tx = threadIdx.x & 31, ty = threadIdx.x >> 5;
#pragma unroll
    for (int i = 0; i < 4; ++i)
        tile[ty + i * 8][tx] = I[(ll)(r0 + ty + i * 8) * C + (c0 + tx)];
    __syncthreads();
#pragma unroll
    for (int i = 0; i < 4; ++i)
        O[(ll)(c0 + ty + i * 8) * R + (r0 + tx)] = f2bf(tile[tx][ty + i * 8]);
}

__global__ void rope_kr(ushort_t* __restrict__ Kp, const float* __restrict__ cb,
                        const float* __restrict__ sb)
{
    int idx = blockIdx.x * 256 + threadIdx.x;   // 2*2048*32
    if (idx >= 2 * 2048 * 32) return;
    int j = idx & 31, t = (idx >> 5) & 2047, b = idx >> 16;
    float c = cb[t * 32 + j], s = sb[t * 32 + j];
    ushort_t* p = Kp + ((ll)(b * 2048 + t)) * 640 + 512 + 2 * j;
    float re = bf2f(p[0]), im = bf2f(p[1]);
    p[0] = f2bf(re * c - im * s);
    p[1] = f2bf(re * s + im * c);
}

__global__ void rope_qr_ip(ushort_t* __restrict__ q, const float* __restrict__ cb,
                           const float* __restrict__ sb)
{
    int idx = blockIdx.x * 256 + threadIdx.x;   // 4096*512 pairs
    if (idx >= 4096 * 512) return;
    int pj = idx & 511, h = pj >> 5, j = pj & 31;
    int row = idx >> 9;
    int t = row & 2047;
    float c = cb[t * 32 + j], s = sb[t * 32 + j];
    ll base = (ll)row * 1024 + h * 64 + 2 * j;
    float re = bf2f(q[base]), im = bf2f(q[base + 1]);
    q[base]     = f2bf(re * c - im * s);
    q[base + 1] = f2bf(re * s + im * c);
}

// ---------------- host-side orchestration ----------------
static inline void gemmb(hipStream_t st, const ushort_t* A, const ushort_t* B, void* C,
                         int M, int N, int K, int a_rs, int b_rs, int c_rs,
                         int nb, int Z2,
                         ll a_bs1, ll a_bs2, ll b_bs1, ll b_bs2, ll c_bs1, ll c_bs2,
                         int of32)
{
    dim3 g(N / TN, M / TM, nb);
    gemm_bf16<<<g, 256, 0, st>>>(A, B, C, M, N, K, a_rs, b_rs, c_rs, Z2,
                                 a_bs1, a_bs2, b_bs1, b_bs2, c_bs1, c_bs2, of32);
}

extern "C" void kernel_launch(void* const* d_in, const int* in_sizes, int n_in,
                              void* d_out, int out_size, void* d_ws, size_t ws_size,
                              hipStream_t stream)
{
    const float* x     = (const float*)d_in[0];
    const float* cosb  = (const float*)d_in[1];
    const float* sinb  = (const float*)d_in[2];
    const float* W_dq  = (const float*)d_in[3];
    const float* W_uq  = (const float*)d_in[4];
    const float* W_dkv = (const float*)d_in[5];
    const float* W_uk  = (const float*)d_in[6];
    const float* W_uv  = (const float*)d_in[7];
    const float* W_qr  = (const float*)d_in[8];
    const float* W_kr  = (const float*)d_in[9];
    const float* W_o   = (const float*)d_in[10];
    float* out = (float*)d_out;

    const float scale = 0.07216878364870323f; // 1/sqrt(128+64)

    // ---- workspace layout (bytes), total ~86.5 MB ----
    char* base = (char*)d_ws;
    ushort_t* Wdq_b   = (ushort_t*)(base + 0);         // [512][2048]        2.10 MB
    ushort_t* Wqr_b   = (ushort_t*)(base + 2097152);   // [1024][512]        1.05
    ushort_t* Wkvr_b  = (ushort_t*)(base + 3145728);   // [640][2048]        2.62
    ushort_t* WukT_b  = (ushort_t*)(base + 5767168);   // [16][512][128]     2.10
    ushort_t* WuvT_b  = (ushort_t*)(base + 7864320);   // [512][2048]        2.10
    ushort_t* WuqT_b  = (ushort_t*)(base + 9961472);   // [2048][512]        2.10
    ushort_t* veffT_b = (ushort_t*)(base + 12058624);  // [16][128][512]     2.10
    ushort_t* Wo_b    = (ushort_t*)(base + 14155776);  // [2048][2048]       8.39
    ushort_t* xb      = (ushort_t*)(base + 22544384);  // [4096][2048]       16.78
    ushort_t* cq_b    = (ushort_t*)(base + 39321600);  // [4096][512]        4.19
    ushort_t* Kp      = (ushort_t*)(base + 43515904);  // [2][2048][640]     5.24
    ushort_t* VT_all  = (ushort_t*)(base + 48758784);  // [2][16][128][2048] 16.78
    ushort_t* q_up    = (ushort_t*)(base + 65536000);  // [4096][2048]       16.78
    ushort_t* qr_b    = (ushort_t*)(base + 82313216);  // [4096][1024]       8.39

    // ---- conversions / transposes ----
    cvt_f32_bf16<<<8192, 256, 0, stream>>>(x, xb, 2097152);
    build_wkvr<<<1280, 256, 0, stream>>>(W_dkv, W_kr, Wkvr_b);
    cvt_f32_bf16<<<1024, 256, 0, stream>>>(W_dq, Wdq_b, 262144);
    cvt_f32_bf16<<<512, 256, 0, stream>>>(W_qr, Wqr_b, 131072);
    cvt_f32_bf16<<<4096, 256, 0, stream>>>(W_o, Wo_b, 1048576);
    transpose_f32_bf16<<<dim3(16, 4, 16), 256, 0, stream>>>(W_uk, WukT_b, 128, 512, 65536, 65536);
    transpose_f32_bf16<<<dim3(16, 64, 1), 256, 0, stream>>>(W_uv, WuvT_b, 2048, 512, 0, 0);
    transpose_f32_bf16<<<dim3(64, 16, 1), 256, 0, stream>>>(W_uq, WuqT_b, 512, 2048, 0, 0);

    // ---- weight precompute: veffT[h][d][k] = sum_c Wo[h*128+d][c] * WuvT[k][c] ----
    gemmb(stream, Wo_b, WuvT_b, veffT_b, 128, 512, 2048, 2048, 2048, 512,
          16, 16, 0, 262144, 0, 0, 0, 65536, 0);

    // ---- projections ----
    gemmb(stream, xb, Wdq_b, cq_b, 4096, 512, 2048, 2048, 2048, 512,
          1, 1, 0, 0, 0, 0, 0, 0, 0);
    gemmb(stream, xb, Wkvr_b, Kp, 4096, 640, 2048, 2048, 2048, 640,
          1, 1, 0, 0, 0, 0, 0, 0, 0);
    rope_kr<<<512, 256, 0, stream>>>(Kp, cosb, sinb);

    // VT[b][h][d][s] = sum_k veffT[h][d][k] * Kp[b][s][k]  (z = b*16+h)
    gemmb(stream, veffT_b, Kp, VT_all, 128, 2048, 512, 512, 640, 2048,
          32, 16, 0, 65536, (ll)2048 * 640, 0, (ll)16 * 262144, 262144, 0);

    // q_up = cq . WuqT^T ; qr = cq . Wqr^T (bf16, rope in place)
    gemmb(stream, cq_b, WuqT_b, q_up, 4096, 2048, 512, 512, 512, 2048,
          1, 1, 0, 0, 0, 0, 0, 0, 0);
    gemmb(stream, cq_b, Wqr_b, qr_b, 4096, 1024, 512, 512, 512, 1024,
          1, 1, 0, 0, 0, 0, 0, 0, 0);
    rope_qr_ip<<<8192, 256, 0, stream>>>(qr_b, cosb, sinb);

    // ---- fused attention ----
    flash_mla<<<dim3(32, 16, 2), 256, 0, stream>>>(q_up, qr_b, WukT_b, Kp, VT_all, out, scale);

    (void)in_sizes; (void)n_in; (void)out_size; (void)ws_size;
}